// Round 3
// baseline (408.489 us; speedup 1.0000x reference)
//
#include <hip/hip_runtime.h>
#include <hip/hip_fp16.h>
#include <math.h>

constexpr int cB   = 4;
constexpr int cNL  = 150;
constexpr int cNP  = 550;
constexpr int cN   = 700;
constexpr int cH   = 128;
constexpr int cHeads = 4;
constexpr int cL   = 6;
constexpr int cK   = 48;
constexpr int cPF  = 27;
constexpr int cNC  = 13;
constexpr int cFLAT = cN * cH;       // 89600
constexpr int cEdges = cB * cN * cK; // 134400

constexpr int   TABN = 4096;
#define TAB_DMAX 11.0f
#define TAB_HT   (TAB_DMAX / (float)(TABN - 1))
#define TAB_INV  ((float)(TABN - 1) / TAB_DMAX)

#define RBF_STEP (10.0f / 127.0f)
#define RBF_COEFF (-0.5f / (RBF_STEP * RBF_STEP))
#define LOG2F_C 0.69314718055994530942f

__device__ __forceinline__ float sspf(float x) {
    float ax = fabsf(x);
    return fmaxf(x, 0.0f) + __logf(1.0f + __expf(-ax)) - LOG2F_C;
}

__device__ __forceinline__ int mbcnt64(unsigned long long m) {
    return __builtin_amdgcn_mbcnt_hi((unsigned)(m >> 32),
           __builtin_amdgcn_mbcnt_lo((unsigned)m, 0));
}

// ---------------- fused: weight repack (lane-contiguous float4 panels) + embedding ----------------
// wqP/wkP/wvP : [l][hh][d4][k][4j]  (float4 idx ((l*4+hh)*8+d4)*32+k)
// wklP        : [l][k4][c][4j]      (float4 idx (l*8+k4)*32+c)
// wvlP        : [l][i4][c][4j]
// cenP/outP   : [l][i4][o][4j]      (float4 idx (l*32+i4)*128+o)
__global__ void __launch_bounds__(256) k_init(
    const float* __restrict__ wq, const float* __restrict__ wk, const float* __restrict__ wv,
    const float* __restrict__ wkn1_w, const float* __restrict__ wvn1_w,
    const float* __restrict__ wkn2_w, const float* __restrict__ wvn2_w,
    const float* __restrict__ wkl_w, const float* __restrict__ wvl_w,
    const float* __restrict__ cen_w, const float* __restrict__ out_w,
    float* __restrict__ wqP, float* __restrict__ wkP, float* __restrict__ wvP,
    float* __restrict__ w1Tk, float* __restrict__ w1Tv,
    float* __restrict__ w2Tk, float* __restrict__ w2Tv,
    float* __restrict__ wklP, float* __restrict__ wvlP,
    float* __restrict__ cenP, float* __restrict__ outP,
    const float* __restrict__ state, const float* __restrict__ ppv,
    const float* __restrict__ w_prot, const float* __restrict__ b_prot,
    const float* __restrict__ w_lig, const float* __restrict__ b_lig,
    float* __restrict__ h, float* __restrict__ pos)
{
    if (blockIdx.x < 1344) {
        int idx = blockIdx.x * 256 + threadIdx.x;
        if (idx < 3 * 24576) {   // qkv packed
            int seg = idx / 24576, i = idx % 24576;
            const float* src = seg == 0 ? wq : (seg == 1 ? wk : wv);
            float* dst = seg == 0 ? wqP : (seg == 1 ? wkP : wvP);
            int j = i & 3, k = (i >> 2) & 31, d4 = (i >> 7) & 7, hl = i >> 10;
            dst[i] = src[((size_t)hl * 32 + k) * 32 + 4 * d4 + j];
            return;
        }
        idx -= 3 * 24576;
        if (idx < 2 * 24576) {   // edge-MLP layer1 transpose (for k_knn table build)
            int seg = idx / 24576, i = idx % 24576;
            const float* src = seg == 0 ? wkn1_w : wvn1_w;
            float* dst = seg == 0 ? w1Tk : w1Tv;
            int l = i / 4096, r = i % 4096;
            int c = r / 32, o = r % 32;
            dst[i] = src[((size_t)l * 32 + o) * 128 + c];
            return;
        }
        idx -= 2 * 24576;
        if (idx < 2 * 6144) {    // edge-MLP layer2 transpose
            int seg = idx / 6144, i = idx % 6144;
            const float* src = seg == 0 ? wkn2_w : wvn2_w;
            float* dst = seg == 0 ? w2Tk : w2Tv;
            int l = i / 1024, r = i % 1024;
            int c = r / 32, o = r % 32;
            dst[i] = src[((size_t)l * 32 + o) * 32 + c];
            return;
        }
        idx -= 2 * 6144;
        if (idx < 6144) {        // wklP packed
            int i = idx;
            int j = i & 3, c = (i >> 2) & 31, k4 = (i >> 7) & 7, l = i >> 10;
            wklP[i] = wkl_w[(size_t)l * 1024 + (4 * k4 + j) * 32 + c];
            return;
        }
        idx -= 6144;
        if (idx < 6144) {        // wvlP packed
            int i = idx;
            int j = i & 3, c = (i >> 2) & 31, i4 = (i >> 7) & 7, l = i >> 10;
            wvlP[i] = wvl_w[((size_t)l * 32 + c) * 32 + 4 * i4 + j];
            return;
        }
        idx -= 6144;
        {                        // cenP/outP packed
            int seg = idx / 98304, i = idx % 98304;
            const float* src = seg == 0 ? cen_w : out_w;
            float* dst = seg == 0 ? cenP : outP;
            int j = i & 3, o = (i >> 2) & 127, i4 = (i >> 9) & 31, l = i >> 14;
            dst[i] = src[((size_t)l * 128 + o) * 128 + 4 * i4 + j];
        }
        return;
    }
    // ---- embed: 2 nodes per block ----
    int rel = blockIdx.x - 1344;
    int node = rel * 2 + (threadIdx.x >> 7);
    int b = node / cN, n = node % cN;
    int o = threadIdx.x & 127;
    int lane = threadIdx.x & 63;
    float out;
    if (n < cNP) {
        const float* src = ppv + ((size_t)b * cNP + n) * 30;
        float v = (lane < 30) ? src[lane] : 0.f;
        float s = b_prot[o];
        #pragma unroll
        for (int f = 0; f < cPF; f++) s += w_prot[o * cPF + f] * __shfl(v, 3 + f);
        out = s;
        if (o < 3) pos[((size_t)b * cN + n) * 3 + o] = v;
    } else {
        int nl = n - cNP;
        const float* src = state + ((size_t)b * cNL + nl) * 4;
        float v = (lane < 4) ? src[lane] : 0.f;
        int t = (int)__shfl(v, 3);
        out = w_lig[o * cNC + t] + b_lig[o];
        if (o < 3) pos[((size_t)b * cN + n) * 3 + o] = v;
    }
    h[((size_t)b * cN + n) * cH + o] = out;
}

// ---------------- KNN (radix-select) + edge-MLP table build (lerp-pair float2) + qkv(l=0) ----------------
__global__ void __launch_bounds__(256) k_knn(
    const float* __restrict__ pos, int* __restrict__ nbr, float* __restrict__ dist,
    const float* __restrict__ w1Tk, const float* __restrict__ wkn1_b,
    const float* __restrict__ w2Tk, const float* __restrict__ wkn2_b,
    const float* __restrict__ w1Tv, const float* __restrict__ wvn1_b,
    const float* __restrict__ w2Tv, const float* __restrict__ wvn2_b,
    float* __restrict__ tabP,
    const float* __restrict__ hbuf,
    const float* __restrict__ wqP, const float* __restrict__ wkP, const float* __restrict__ wvP,
    float* __restrict__ q0, __half* __restrict__ kx0, __half* __restrict__ vx0)
{
    int tid = threadIdx.x;
    if (blockIdx.x < cN) {
        // ---- knn: one wave per node, radix-select on float bit patterns ----
        int lane = tid & 63;
        int node = blockIdx.x * 4 + (tid >> 6);
        int b = node / cN, n = node % cN;
        const float* pb = pos + (size_t)b * cN * 3;
        float px = pb[n * 3 + 0], py = pb[n * 3 + 1], pz = pb[n * 3 + 2];
        float d2v[11];
        #pragma unroll
        for (int s = 0; s < 11; s++) {
            int j = lane + s * 64;
            float d2 = 1e30f;
            if (j < cN) {
                float dx = pb[j * 3 + 0] - px;
                float dy = pb[j * 3 + 1] - py;
                float dz = pb[j * 3 + 2] - pz;
                d2 = dx * dx + dy * dy + dz * dz;
                if (j == n) d2 = 1e9f;
            }
            d2v[s] = d2;
        }
        unsigned p = 0;
        for (int bit = 30; bit >= 0; --bit) {
            unsigned t = p | (1u << bit);
            int cnt = 0;
            #pragma unroll
            for (int s = 0; s < 11; s++)
                cnt += __popcll(__ballot(__float_as_uint(d2v[s]) < t));
            if (cnt <= 47) p = t;
        }
        int c_lt = 0;
        #pragma unroll
        for (int s = 0; s < 11; s++)
            c_lt += __popcll(__ballot(__float_as_uint(d2v[s]) < p));
        int base = 0, ebase = c_lt, need = 48 - c_lt;
        #pragma unroll
        for (int s = 0; s < 11; s++) {
            unsigned u = __float_as_uint(d2v[s]);
            unsigned long long blt = __ballot(u < p);
            unsigned long long beq = __ballot(u == p);
            int posn = -1;
            int bl = mbcnt64(blt);
            if (u < p) posn = base + bl;
            base += __popcll(blt);
            int r = mbcnt64(beq);
            int cs = __popcll(beq);
            int take = need < cs ? need : cs;
            if (u == p && r < take) posn = ebase + r;
            ebase += take; need -= take;
            if (posn >= 0) {
                nbr[(size_t)node * cK + posn] = s * 64 + lane;
                dist[(size_t)node * cK + posn] = sqrtf(d2v[s]);
            }
        }
        return;
    }
    if (blockIdx.x < cN + TABN / 4) {
        // ---- table build: wave per entry; stores {val[e] (.x of e), val[e] (.y of e-1)} ----
        int rel = blockIdx.x - cN;
        int lane = tid & 63;
        int e = rel * 4 + (tid >> 6);
        int side = lane >> 5, o = lane & 31;
        float d = (float)e * TAB_HT;
        float z = d * (127.0f / 10.0f);
        int c0 = (int)floorf(z) - 7;
        c0 = c0 < 0 ? 0 : (c0 > 112 ? 112 : c0);
        int i = lane & 15;
        float tt = d - RBF_STEP * (float)(c0 + i);
        float eav = __expf(RBF_COEFF * tt * tt);
        const float* w1T = (side ? w1Tv : w1Tk);
        const float* b1  = (side ? wvn1_b : wkn1_b);
        const float* w2T = (side ? w2Tv : w2Tk);
        const float* b2  = (side ? wvn2_b : wkn2_b);
        int srcb = side * 32;
        for (int l = 0; l < cL; l++) {
            float s = b1[l * 32 + o];
            const float* w1p = w1T + (size_t)l * 4096;
            #pragma unroll
            for (int ii = 0; ii < 16; ii++)
                s += w1p[(c0 + ii) * 32 + o] * __shfl(eav, ii);
            float t1 = sspf(s);
            float s2 = b2[l * 32 + o];
            const float* w2p = w2T + (size_t)l * 1024;
            #pragma unroll
            for (int cc = 0; cc < 32; cc++)
                s2 += w2p[cc * 32 + o] * __shfl(t1, srcb + cc);
            // packed lerp-pair layout: float2 slot [(l*TABN+e)*2+side][c]
            tabP[((((size_t)l * TABN + e) * 2 + side) * 32 + o) * 2] = s2;
            if (e > 0)
                tabP[((((size_t)l * TABN + (e - 1)) * 2 + side) * 32 + o) * 2 + 1] = s2;
        }
        return;
    }
    // ---- qkv for layer 0: 2 nodes per block, packed float4 weights ----
    int bn = (blockIdx.x - cN - TABN / 4) * 2 + (tid >> 7);
    int o = tid & 127;
    int hh = o >> 5, kq = o & 31;
    float hval = hbuf[(size_t)bn * cH + o];
    int srcb = (hh & 1) * 32;
    const float4* bq4 = (const float4*)wqP + (size_t)hh * 256 + kq;
    const float4* bk4 = (const float4*)wkP + (size_t)hh * 256 + kq;
    const float4* bv4 = (const float4*)wvP + (size_t)hh * 256 + kq;
    float sq = 0.f, sk = 0.f, sv = 0.f;
    #pragma unroll
    for (int d4 = 0; d4 < 8; d4++) {
        float4 a = bq4[d4 * 32], b4 = bk4[d4 * 32], v4 = bv4[d4 * 32];
        float x0 = __shfl(hval, srcb + 4 * d4 + 0);
        float x1 = __shfl(hval, srcb + 4 * d4 + 1);
        float x2 = __shfl(hval, srcb + 4 * d4 + 2);
        float x3 = __shfl(hval, srcb + 4 * d4 + 3);
        sq += a.x * x0 + a.y * x1 + a.z * x2 + a.w * x3;
        sk += b4.x * x0 + b4.y * x1 + b4.z * x2 + b4.w * x3;
        sv += v4.x * x0 + v4.y * x1 + v4.z * x2 + v4.w * x3;
    }
    q0[(size_t)bn * cH + o] = sq;
    kx0[(size_t)bn * cH + o] = __float2half(sk);
    vx0[(size_t)bn * cH + o] = __float2half(sv);
}

// ---------------- fused attention + LN + residual MLP + next-layer qkv ----------------
// ONE node per 128-thread block (2 waves), packed float4/float2 loads throughout.
__global__ void __launch_bounds__(128) k_attn(
    int l,
    const float* __restrict__ h_in, const float* __restrict__ qr,
    const __half* __restrict__ kxr, const __half* __restrict__ vxr,
    const int* __restrict__ nbr, const float* __restrict__ dist,
    const float* __restrict__ tabP,
    const float* __restrict__ wklP,
    const float* __restrict__ wvlP, const float* __restrict__ wvl_b,
    const float* __restrict__ cenP, const float* __restrict__ cen_b,
    const float* __restrict__ outP, const float* __restrict__ out_b,
    const float* __restrict__ ln_g, const float* __restrict__ ln_b,
    float* __restrict__ h_out,
    float* __restrict__ qw, __half* __restrict__ kxw, __half* __restrict__ vxw,
    const float* __restrict__ wqP, const float* __restrict__ wkP, const float* __restrict__ wvP)
{
    int o = threadIdx.x;              // 0..127
    int bn = blockIdx.x;
    int b = bn / cN;
    int hh = o >> 5, c = o & 31;
    int srcb = (hh & 1) * 32;

    __shared__ __align__(16) float sh_h[cH];
    __shared__ __align__(16) float sh_t[cH];
    __shared__ float sh_qk[cK * cHeads];
    __shared__ int   sh_nb[cK];
    __shared__ int   sh_idx[cK];
    __shared__ float sh_frac[cK];
    __shared__ float red[2][2];

    sh_h[o] = h_in[(size_t)bn * cH + o];
    float qv = qr[(size_t)bn * cH + o];
    if (o < cK) {
        sh_nb[o] = nbr[(size_t)bn * cK + o];
        float d = dist[(size_t)bn * cK + o];
        float z = d * TAB_INV;
        int idx = (int)z;
        if (idx > TABN - 2) idx = TABN - 2;
        sh_idx[o] = idx;
        sh_frac[o] = fminf(z - (float)idx, 1.0f);
    }
    __syncthreads();

    // qt[h,c] = sum_k q[h,k]*wkl[k,c]  (bias cancels in softmax); packed float4
    const float4* wklp4 = (const float4*)wklP + (size_t)l * 256 + c;
    float qt = 0.f;
    #pragma unroll
    for (int k4 = 0; k4 < 8; k4++) {
        float4 w4 = wklp4[k4 * 32];
        qt += w4.x * __shfl(qv, srcb + 4 * k4 + 0)
            + w4.y * __shfl(qv, srcb + 4 * k4 + 1)
            + w4.z * __shfl(qv, srcb + 4 * k4 + 2)
            + w4.w * __shfl(qv, srcb + 4 * k4 + 3);
    }

    const __half* kxb = kxr + (size_t)b * cN * cH;
    const __half* vxb = vxr + (size_t)b * cN * cH;
    const float2* tab2 = (const float2*)tabP + (size_t)l * TABN * 64;

    // pass 1: logits (single-load lerp pairs), two edges per butterfly
    #pragma unroll 4
    for (int m = 0; m < cK; m += 2) {
        int j0 = sh_nb[m], j1 = sh_nb[m + 1];
        float k0 = __half2float(kxb[(size_t)j0 * cH + o]);
        float k1 = __half2float(kxb[(size_t)j1 * cH + o]);
        float2 t0 = tab2[((size_t)sh_idx[m] * 2 + 0) * 32 + c];
        float2 t1 = tab2[((size_t)sh_idx[m + 1] * 2 + 0) * 32 + c];
        float w0 = t0.x + sh_frac[m] * (t0.y - t0.x);
        float w1 = t1.x + sh_frac[m + 1] * (t1.y - t1.x);
        float pa = qt * w0 * k0;
        float pb = qt * w1 * k1;
        float x = (c & 1) ? pb : pa;
        float y = (c & 1) ? pa : pb;
        x += __shfl_xor(y, 1);
        x += __shfl_xor(x, 2);
        x += __shfl_xor(x, 4);
        x += __shfl_xor(x, 8);
        x += __shfl_xor(x, 16);
        if (c < 2) sh_qk[(m + c) * cHeads + hh] = x;
    }
    __syncthreads();

    // softmax over m per head
    {
        float v1 = sh_qk[c * cHeads + hh];
        float v2 = (c < cK - 32) ? sh_qk[(32 + c) * cHeads + hh] : -1e30f;
        float mx = fmaxf(v1, v2);
        #pragma unroll
        for (int off = 16; off; off >>= 1) mx = fmaxf(mx, __shfl_xor(mx, off));
        float e1 = __expf(v1 - mx);
        float e2 = (c < cK - 32) ? __expf(v2 - mx) : 0.f;
        float s = e1 + e2;
        #pragma unroll
        for (int off = 16; off; off >>= 1) s += __shfl_xor(s, off);
        float inv = 1.0f / s;
        sh_qk[c * cHeads + hh] = e1 * inv;
        if (c < cK - 32) sh_qk[(32 + c) * cHeads + hh] = e2 * inv;
    }
    __syncthreads();

    // pass 2: t[h,c] = sum_m alpha*w_v*vx ; single-load lerp pairs, dual accumulators
    float t0a = 0.f, t1a = 0.f;
    #pragma unroll 4
    for (int m = 0; m < cK; m += 2) {
        int j0 = sh_nb[m], j1 = sh_nb[m + 1];
        float v0 = __half2float(vxb[(size_t)j0 * cH + o]);
        float v1 = __half2float(vxb[(size_t)j1 * cH + o]);
        float2 s0 = tab2[((size_t)sh_idx[m] * 2 + 1) * 32 + c];
        float2 s1 = tab2[((size_t)sh_idx[m + 1] * 2 + 1) * 32 + c];
        float w0 = s0.x + sh_frac[m] * (s0.y - s0.x);
        float w1 = s1.x + sh_frac[m + 1] * (s1.y - s1.x);
        t0a += sh_qk[m * cHeads + hh] * (w0 * v0);
        t1a += sh_qk[(m + 1) * cHeads + hh] * (w1 * v1);
    }
    sh_t[o] = t0a + t1a;
    __syncthreads();

    // aggr[c] = wvl_b + sum_i wvl[c][i]*t[h,i]  (packed float4, LDS float4 reads)
    const float4* wvlp4 = (const float4*)wvlP + (size_t)l * 256 + c;
    const float4* st4 = (const float4*)&sh_t[hh * 32];
    float aggr = wvl_b[l * 32 + c];
    #pragma unroll
    for (int i4 = 0; i4 < 8; i4++) {
        float4 w4 = wvlp4[i4 * 32];
        float4 t4 = st4[i4];
        aggr += w4.x * t4.x + w4.y * t4.y + w4.z * t4.z + w4.w * t4.w;
    }

    // x = cen_b + aggr + cen_w[o,:] . h  (packed float4 panels)
    const float4* cenp4 = (const float4*)cenP + (size_t)l * 4096 + o;
    const float4* sh4 = (const float4*)sh_h;
    float xa = 0.f, xb = 0.f;
    #pragma unroll 4
    for (int i4 = 0; i4 < 32; i4 += 2) {
        float4 wa = cenp4[i4 * 128], wb = cenp4[(i4 + 1) * 128];
        float4 ha = sh4[i4], hb = sh4[i4 + 1];
        xa += wa.x * ha.x + wa.y * ha.y + wa.z * ha.z + wa.w * ha.w;
        xb += wb.x * hb.x + wb.y * hb.y + wb.z * hb.z + wb.w * hb.w;
    }
    float x = cen_b[l * cH + o] + aggr + xa + xb;

    // LayerNorm
    float s1 = x, s2 = x * x;
    #pragma unroll
    for (int off = 32; off; off >>= 1) {
        s1 += __shfl_xor(s1, off);
        s2 += __shfl_xor(s2, off);
    }
    int wid = o >> 6;
    if ((o & 63) == 0) { red[wid][0] = s1; red[wid][1] = s2; }
    __syncthreads();
    float tot1 = red[0][0] + red[1][0], tot2 = red[0][1] + red[1][1];
    float mu = tot1 * (1.0f / 128.0f);
    float var = tot2 * (1.0f / 128.0f) - mu * mu;
    float xn = (x - mu) * rsqrtf(var + 1e-5f);
    xn = xn * ln_g[l * cH + o] + ln_b[l * cH + o];
    float sx = sspf(xn);
    sh_t[o] = sx;   // safe: all sh_t readers passed the red-sync above
    __syncthreads();

    // hnew = h + out_b + out_w[o,:] . ssp(xn)  (packed float4 panels)
    const float4* outp4 = (const float4*)outP + (size_t)l * 4096 + o;
    const float4* st4b = (const float4*)sh_t;
    float oa = 0.f, ob = 0.f;
    #pragma unroll 4
    for (int i4 = 0; i4 < 32; i4 += 2) {
        float4 wa = outp4[i4 * 128], wb = outp4[(i4 + 1) * 128];
        float4 ta = st4b[i4], tb = st4b[i4 + 1];
        oa += wa.x * ta.x + wa.y * ta.y + wa.z * ta.z + wa.w * ta.w;
        ob += wb.x * tb.x + wb.y * tb.y + wb.z * tb.z + wb.w * tb.w;
    }
    float hnew = sh_h[o] + out_b[l * cH + o] + oa + ob;
    h_out[(size_t)bn * cH + o] = hnew;

    // ---- fused qkv for layer l+1 (packed float4 weights) ----
    if (l < cL - 1) {
        size_t wo = ((size_t)(l + 1) * 4 + hh) * 256 + c;
        const float4* bq4 = (const float4*)wqP + wo;
        const float4* bk4 = (const float4*)wkP + wo;
        const float4* bv4 = (const float4*)wvP + wo;
        float sq = 0.f, sk = 0.f, sv = 0.f;
        #pragma unroll
        for (int d4 = 0; d4 < 8; d4++) {
            float4 a = bq4[d4 * 32], b4 = bk4[d4 * 32], v4 = bv4[d4 * 32];
            float x0 = __shfl(hnew, srcb + 4 * d4 + 0);
            float x1 = __shfl(hnew, srcb + 4 * d4 + 1);
            float x2 = __shfl(hnew, srcb + 4 * d4 + 2);
            float x3 = __shfl(hnew, srcb + 4 * d4 + 3);
            sq += a.x * x0 + a.y * x1 + a.z * x2 + a.w * x3;
            sk += b4.x * x0 + b4.y * x1 + b4.z * x2 + b4.w * x3;
            sv += v4.x * x0 + v4.y * x1 + v4.z * x2 + v4.w * x3;
        }
        qw[(size_t)bn * cH + o] = sq;
        kxw[(size_t)bn * cH + o] = __float2half(sk);
        vxw[(size_t)bn * cH + o] = __float2half(sv);
    }
}

// ---------------- FC head ----------------
__global__ void __launch_bounds__(256) k_fc1p(const float* __restrict__ hbuf,
                                              const float* __restrict__ w,
                                              float* __restrict__ partial)
{
    int o = blockIdx.x >> 2, qp = blockIdx.x & 3;
    int tid = threadIdx.x;
    constexpr int CH = cFLAT / 4;
    const float4* wr = (const float4*)(w + (size_t)o * cFLAT + qp * CH);
    float a[4] = {0.f, 0.f, 0.f, 0.f};
    for (int i = tid; i < CH / 4; i += 256) {
        float4 wv = wr[i];
        #pragma unroll
        for (int bb = 0; bb < 4; bb++) {
            float4 hv = ((const float4*)(hbuf + (size_t)bb * cFLAT + qp * CH))[i];
            a[bb] += wv.x * hv.x + wv.y * hv.y + wv.z * hv.z + wv.w * hv.w;
        }
    }
    #pragma unroll
    for (int off = 32; off; off >>= 1) {
        #pragma unroll
        for (int bb = 0; bb < 4; bb++) a[bb] += __shfl_xor(a[bb], off);
    }
    __shared__ float red[4][4];
    if ((tid & 63) == 0) {
        #pragma unroll
        for (int bb = 0; bb < 4; bb++) red[tid >> 6][bb] = a[bb];
    }
    __syncthreads();
    if (tid < 4) {
        float s = red[0][tid] + red[1][tid] + red[2][tid] + red[3][tid];
        partial[((size_t)o * 4 + qp) * 4 + tid] = s;
    }
}

__global__ void __launch_bounds__(512) k_head2(const float* __restrict__ partial,
                                               const float* __restrict__ fc1_b,
                                               const float* __restrict__ fc2_w,
                                               const float* __restrict__ fc2_b,
                                               const float* __restrict__ fc3_w,
                                               const float* __restrict__ fc3_b,
                                               float* __restrict__ out)
{
    int tid = threadIdx.x;
    __shared__ float y1[4][128];
    __shared__ float y2[4][64];
    {
        int bb = tid >> 7, o = tid & 127;
        float s = fc1_b[o];
        #pragma unroll
        for (int qp = 0; qp < 4; qp++) s += partial[((size_t)o * 4 + qp) * 4 + bb];
        y1[bb][o] = fmaxf(s, 0.f);
    }
    __syncthreads();
    if (tid < 256) {
        int bb = tid >> 6, o = tid & 63;
        float s = fc2_b[o];
        #pragma unroll 8
        for (int i = 0; i < 128; i++) s += fc2_w[o * 128 + i] * y1[bb][i];
        y2[bb][o] = fmaxf(s, 0.f);
    }
    __syncthreads();
    if (tid < 4) {
        float s = fc3_b[0];
        #pragma unroll 8
        for (int i = 0; i < 64; i++) s += fc3_w[i] * y2[tid][i];
        out[tid] = s;
    }
}

extern "C" void kernel_launch(void* const* d_in, const int* in_sizes, int n_in,
                              void* d_out, int out_size, void* d_ws, size_t ws_size,
                              hipStream_t stream) {
    const float* state  = (const float*)d_in[0];
    const float* ppv    = (const float*)d_in[1];
    const float* w_prot = (const float*)d_in[2];
    const float* b_prot = (const float*)d_in[3];
    const float* w_lig  = (const float*)d_in[4];
    const float* b_lig  = (const float*)d_in[5];
    const float* wq     = (const float*)d_in[6];
    const float* wk     = (const float*)d_in[7];
    const float* wv     = (const float*)d_in[8];
    const float* wkn1_w = (const float*)d_in[9];
    const float* wkn1_b = (const float*)d_in[10];
    const float* wkn2_w = (const float*)d_in[11];
    const float* wkn2_b = (const float*)d_in[12];
    const float* wkl_w  = (const float*)d_in[13];
    const float* wvn1_w = (const float*)d_in[15];
    const float* wvn1_b = (const float*)d_in[16];
    const float* wvn2_w = (const float*)d_in[17];
    const float* wvn2_b = (const float*)d_in[18];
    const float* wvl_w  = (const float*)d_in[19];
    const float* wvl_b  = (const float*)d_in[20];
    const float* cen_w  = (const float*)d_in[21];
    const float* cen_b  = (const float*)d_in[22];
    const float* out_w  = (const float*)d_in[23];
    const float* out_b  = (const float*)d_in[24];
    const float* ln_g   = (const float*)d_in[25];
    const float* ln_b   = (const float*)d_in[26];
    const float* fc1_w  = (const float*)d_in[27];
    const float* fc1_b  = (const float*)d_in[28];
    const float* fc2_w  = (const float*)d_in[29];
    const float* fc2_b  = (const float*)d_in[30];
    const float* fc3_w  = (const float*)d_in[31];
    const float* fc3_b  = (const float*)d_in[32];

    float* ws = (float*)d_ws;
    size_t off = 0;
    float* pos   = ws + off; off += (size_t)cB * cN * 3;
    float* h_a   = ws + off; off += (size_t)cB * cN * cH;
    float* h_b   = ws + off; off += (size_t)cB * cN * cH;
    float* qA    = ws + off; off += (size_t)cB * cN * cH;
    float* qB    = ws + off; off += (size_t)cB * cN * cH;
    __half* kA   = (__half*)(ws + off); off += (size_t)cB * cN * cH / 2;
    __half* vA   = (__half*)(ws + off); off += (size_t)cB * cN * cH / 2;
    __half* kB   = (__half*)(ws + off); off += (size_t)cB * cN * cH / 2;
    __half* vB   = (__half*)(ws + off); off += (size_t)cB * cN * cH / 2;
    float* distb = ws + off; off += (size_t)cEdges;
    int*   nbrb  = (int*)(ws + off); off += (size_t)cEdges;
    float* tabb  = ws + off; off += (size_t)cL * TABN * 64 * 2;  // 3.15M floats (lerp-pair float2)
    float* wqP   = ws + off; off += 24576;
    float* wkP   = ws + off; off += 24576;
    float* wvP   = ws + off; off += 24576;
    float* w1Tk  = ws + off; off += 24576;
    float* w1Tv  = ws + off; off += 24576;
    float* w2Tk  = ws + off; off += 6144;
    float* w2Tv  = ws + off; off += 6144;
    float* wklP  = ws + off; off += 6144;
    float* wvlP  = ws + off; off += 6144;
    float* cenP  = ws + off; off += 98304;
    float* outP  = ws + off; off += 98304;
    float* partial = ws + off; off += 2048;

    k_init<<<1344 + cB * cN / 2, 256, 0, stream>>>(
        wq, wk, wv, wkn1_w, wvn1_w, wkn2_w, wvn2_w, wkl_w, wvl_w, cen_w, out_w,
        wqP, wkP, wvP, w1Tk, w1Tv, w2Tk, w2Tv, wklP, wvlP, cenP, outP,
        state, ppv, w_prot, b_prot, w_lig, b_lig, h_a, pos);
    k_knn<<<cN + TABN / 4 + cB * cN / 2, 256, 0, stream>>>(
        pos, nbrb, distb,
        w1Tk, wkn1_b, w2Tk, wkn2_b, w1Tv, wvn1_b, w2Tv, wvn2_b, tabb,
        h_a, wqP, wkP, wvP, qA, kA, vA);

    float* hc = h_a;
    float* hn = h_b;
    for (int l = 0; l < cL; l++) {
        float* qr = (l & 1) ? qB : qA;
        __half* kr = (l & 1) ? kB : kA;
        __half* vr = (l & 1) ? vB : vA;
        float* qw2 = (l & 1) ? qA : qB;
        __half* kw2 = (l & 1) ? kA : kB;
        __half* vw2 = (l & 1) ? vA : vB;
        k_attn<<<cB * cN, 128, 0, stream>>>(l, hc, qr, kr, vr, nbrb, distb, tabb,
            wklP, wvlP, wvl_b, cenP, cen_b, outP, out_b, ln_g, ln_b,
            hn, qw2, kw2, vw2, wqP, wkP, wvP);
        float* tmp = hc; hc = hn; hn = tmp;
    }

    k_fc1p<<<512, 256, 0, stream>>>(hc, fc1_w, partial);
    k_head2<<<1, 512, 0, stream>>>(partial, fc1_b, fc2_w, fc2_b, fc3_w, fc3_b, (float*)d_out);
}

// Round 4
// 386.437 us; speedup vs baseline: 1.0571x; 1.0571x over previous
//
#include <hip/hip_runtime.h>
#include <hip/hip_fp16.h>
#include <math.h>

constexpr int cB   = 4;
constexpr int cNL  = 150;
constexpr int cNP  = 550;
constexpr int cN   = 700;
constexpr int cH   = 128;
constexpr int cHeads = 4;
constexpr int cL   = 6;
constexpr int cK   = 48;
constexpr int cPF  = 27;
constexpr int cNC  = 13;
constexpr int cFLAT = cN * cH;       // 89600
constexpr int cEdges = cB * cN * cK; // 134400

constexpr int   TABN = 4096;
#define TAB_DMAX 11.0f
#define TAB_HT   (TAB_DMAX / (float)(TABN - 1))
#define TAB_INV  ((float)(TABN - 1) / TAB_DMAX)

#define RBF_STEP (10.0f / 127.0f)
#define RBF_COEFF (-0.5f / (RBF_STEP * RBF_STEP))
#define LOG2F_C 0.69314718055994530942f

__device__ __forceinline__ float sspf(float x) {
    float ax = fabsf(x);
    return fmaxf(x, 0.0f) + __logf(1.0f + __expf(-ax)) - LOG2F_C;
}

__device__ __forceinline__ int mbcnt64(unsigned long long m) {
    return __builtin_amdgcn_mbcnt_hi((unsigned)(m >> 32),
           __builtin_amdgcn_mbcnt_lo((unsigned)m, 0));
}

// ---------------- fused: weight transposes + embedding ----------------
__global__ void __launch_bounds__(256) k_init(
    const float* __restrict__ wq, const float* __restrict__ wk, const float* __restrict__ wv,
    const float* __restrict__ wkn1_w, const float* __restrict__ wvn1_w,
    const float* __restrict__ wkn2_w, const float* __restrict__ wvn2_w,
    const float* __restrict__ wvl_w,
    const float* __restrict__ cen_w, const float* __restrict__ out_w,
    float* __restrict__ wqT, float* __restrict__ wkT, float* __restrict__ wvT,
    float* __restrict__ w1Tk, float* __restrict__ w1Tv,
    float* __restrict__ w2Tk, float* __restrict__ w2Tv,
    float* __restrict__ wvlT,
    float* __restrict__ cenT, float* __restrict__ outT,
    const float* __restrict__ state, const float* __restrict__ ppv,
    const float* __restrict__ w_prot, const float* __restrict__ b_prot,
    const float* __restrict__ w_lig, const float* __restrict__ b_lig,
    float* __restrict__ h, float* __restrict__ pos)
{
    if (blockIdx.x < 1320) {
        int idx = blockIdx.x * 256 + threadIdx.x;
        if (idx < 3 * 24576) {
            int seg = idx / 24576, i = idx % 24576;
            const float* src = seg == 0 ? wq : (seg == 1 ? wk : wv);
            float* dst = seg == 0 ? wqT : (seg == 1 ? wkT : wvT);
            int l = i / 4096, r = i % 4096;
            int hh = r / 1024, r2 = r % 1024;
            int d = r2 / 32, k = r2 % 32;
            dst[i] = src[(((size_t)l * 4 + hh) * 32 + k) * 32 + d];
            return;
        }
        idx -= 3 * 24576;
        if (idx < 2 * 24576) {
            int seg = idx / 24576, i = idx % 24576;
            const float* src = seg == 0 ? wkn1_w : wvn1_w;
            float* dst = seg == 0 ? w1Tk : w1Tv;
            int l = i / 4096, r = i % 4096;
            int c = r / 32, o = r % 32;
            dst[i] = src[((size_t)l * 32 + o) * 128 + c];
            return;
        }
        idx -= 2 * 24576;
        if (idx < 3 * 6144) {
            int seg = idx / 6144, i = idx % 6144;
            const float* src = seg == 0 ? wkn2_w : (seg == 1 ? wvn2_w : wvl_w);
            float* dst = seg == 0 ? w2Tk : (seg == 1 ? w2Tv : wvlT);
            int l = i / 1024, r = i % 1024;
            int c = r / 32, o = r % 32;
            dst[i] = src[((size_t)l * 32 + o) * 32 + c];
            return;
        }
        idx -= 3 * 6144;
        int seg = idx / 98304, i = idx % 98304;
        const float* src = seg == 0 ? cen_w : out_w;
        float* dst = seg == 0 ? cenT : outT;
        int l = i / 16384, r = i % 16384;
        int ii = r / 128, o = r % 128;
        dst[i] = src[((size_t)l * 128 + o) * 128 + ii];
        return;
    }
    // ---- embed: 2 nodes per block ----
    int rel = blockIdx.x - 1320;
    int node = rel * 2 + (threadIdx.x >> 7);
    int b = node / cN, n = node % cN;
    int o = threadIdx.x & 127;
    int lane = threadIdx.x & 63;
    float out;
    if (n < cNP) {
        const float* src = ppv + ((size_t)b * cNP + n) * 30;
        float v = (lane < 30) ? src[lane] : 0.f;
        float s = b_prot[o];
        #pragma unroll
        for (int f = 0; f < cPF; f++) s += w_prot[o * cPF + f] * __shfl(v, 3 + f);
        out = s;
        if (o < 3) pos[((size_t)b * cN + n) * 3 + o] = v;
    } else {
        int nl = n - cNP;
        const float* src = state + ((size_t)b * cNL + nl) * 4;
        float v = (lane < 4) ? src[lane] : 0.f;
        int t = (int)__shfl(v, 3);
        out = w_lig[o * cNC + t] + b_lig[o];
        if (o < 3) pos[((size_t)b * cN + n) * 3 + o] = v;
    }
    h[((size_t)b * cN + n) * cH + o] = out;
}

// ---------------- KNN (radix-select) + edge-MLP table build + qkv(l=0) ----------------
__global__ void __launch_bounds__(256) k_knn(
    const float* __restrict__ pos, int* __restrict__ nbr, float* __restrict__ dist,
    const float* __restrict__ w1Tk, const float* __restrict__ wkn1_b,
    const float* __restrict__ w2Tk, const float* __restrict__ wkn2_b,
    const float* __restrict__ w1Tv, const float* __restrict__ wvn1_b,
    const float* __restrict__ w2Tv, const float* __restrict__ wvn2_b,
    float* __restrict__ tab,
    const float* __restrict__ hbuf,
    const float* __restrict__ wqT, const float* __restrict__ wkT, const float* __restrict__ wvT,
    float* __restrict__ q0, __half* __restrict__ kx0, __half* __restrict__ vx0)
{
    int tid = threadIdx.x;
    if (blockIdx.x < cN) {
        // ---- knn: one wave per node, radix-select on float bit patterns ----
        int lane = tid & 63;
        int node = blockIdx.x * 4 + (tid >> 6);
        int b = node / cN, n = node % cN;
        const float* pb = pos + (size_t)b * cN * 3;
        float px = pb[n * 3 + 0], py = pb[n * 3 + 1], pz = pb[n * 3 + 2];
        float d2v[11];
        #pragma unroll
        for (int s = 0; s < 11; s++) {
            int j = lane + s * 64;
            float d2 = 1e30f;
            if (j < cN) {
                float dx = pb[j * 3 + 0] - px;
                float dy = pb[j * 3 + 1] - py;
                float dz = pb[j * 3 + 2] - pz;
                d2 = dx * dx + dy * dy + dz * dz;
                if (j == n) d2 = 1e9f;
            }
            d2v[s] = d2;
        }
        unsigned p = 0;
        for (int bit = 30; bit >= 0; --bit) {
            unsigned t = p | (1u << bit);
            int cnt = 0;
            #pragma unroll
            for (int s = 0; s < 11; s++)
                cnt += __popcll(__ballot(__float_as_uint(d2v[s]) < t));
            if (cnt <= 47) p = t;
        }
        int c_lt = 0;
        #pragma unroll
        for (int s = 0; s < 11; s++)
            c_lt += __popcll(__ballot(__float_as_uint(d2v[s]) < p));
        int base = 0, ebase = c_lt, need = 48 - c_lt;
        #pragma unroll
        for (int s = 0; s < 11; s++) {
            unsigned u = __float_as_uint(d2v[s]);
            unsigned long long blt = __ballot(u < p);
            unsigned long long beq = __ballot(u == p);
            int posn = -1;
            int bl = mbcnt64(blt);
            if (u < p) posn = base + bl;
            base += __popcll(blt);
            int r = mbcnt64(beq);
            int cs = __popcll(beq);
            int take = need < cs ? need : cs;
            if (u == p && r < take) posn = ebase + r;
            ebase += take; need -= take;
            if (posn >= 0) {
                nbr[(size_t)node * cK + posn] = s * 64 + lane;
                dist[(size_t)node * cK + posn] = sqrtf(d2v[s]);
            }
        }
        return;
    }
    if (blockIdx.x < cN + TABN / 4) {
        // ---- table build: wave per entry, loops all L layers ----
        int rel = blockIdx.x - cN;
        int lane = tid & 63;
        int e = rel * 4 + (tid >> 6);
        int side = lane >> 5, o = lane & 31;
        float d = (float)e * TAB_HT;
        float z = d * (127.0f / 10.0f);
        int c0 = (int)floorf(z) - 7;
        c0 = c0 < 0 ? 0 : (c0 > 112 ? 112 : c0);
        int i = lane & 15;
        float tt = d - RBF_STEP * (float)(c0 + i);
        float eav = __expf(RBF_COEFF * tt * tt);
        const float* w1T = (side ? w1Tv : w1Tk);
        const float* b1  = (side ? wvn1_b : wkn1_b);
        const float* w2T = (side ? w2Tv : w2Tk);
        const float* b2  = (side ? wvn2_b : wkn2_b);
        int srcb = side * 32;
        for (int l = 0; l < cL; l++) {
            float s = b1[l * 32 + o];
            const float* w1p = w1T + (size_t)l * 4096;
            #pragma unroll
            for (int ii = 0; ii < 16; ii++)
                s += w1p[(c0 + ii) * 32 + o] * __shfl(eav, ii);
            float t1 = sspf(s);
            float s2 = b2[l * 32 + o];
            const float* w2p = w2T + (size_t)l * 1024;
            #pragma unroll
            for (int cc = 0; cc < 32; cc++)
                s2 += w2p[cc * 32 + o] * __shfl(t1, srcb + cc);
            tab[((size_t)(l * TABN + e) * 2 + side) * 32 + o] = s2;
        }
        return;
    }
    // ---- qkv for layer 0: 2 nodes per block ----
    int bn = (blockIdx.x - cN - TABN / 4) * 2 + (tid >> 7);
    int o = tid & 127;
    int hh = o >> 5, kq = o & 31;
    float hval = hbuf[(size_t)bn * cH + o];
    size_t wo = ((size_t)0 * 4 + hh) * 1024;
    const float* bq = wqT + wo;
    const float* bk = wkT + wo;
    const float* bv = wvT + wo;
    int srcb = (hh & 1) * 32;
    float sq = 0.f, sk = 0.f, sv = 0.f;
    #pragma unroll
    for (int d = 0; d < 32; d++) {
        float x = __shfl(hval, srcb + d);
        sq += bq[d * 32 + kq] * x;
        sk += bk[d * 32 + kq] * x;
        sv += bv[d * 32 + kq] * x;
    }
    q0[(size_t)bn * cH + o] = sq;
    kx0[(size_t)bn * cH + o] = __float2half(sk);
    vx0[(size_t)bn * cH + o] = __float2half(sv);
}

// ---------------- fused attention + LN + residual MLP + next-layer qkv ----------------
// 2 nodes per 256-thread block (round-0 structure), plus:
//  (1) LDS-staged lerped edge weights (tab 4x dedup: 192 -> 48 loads/thread)
//  (2) cross-node weight sharing for cen/out/wvl (i-range split across g-halves,
//      each weight load used for both nodes; partials combined via LDS)
__global__ void __launch_bounds__(256) k_attn(
    int l,
    const float* __restrict__ h_in, const float* __restrict__ qr,
    const __half* __restrict__ kxr, const __half* __restrict__ vxr,
    const int* __restrict__ nbr, const float* __restrict__ dist,
    const float* __restrict__ tab,
    const float* __restrict__ wkl_w,
    const float* __restrict__ wvlT, const float* __restrict__ wvl_b,
    const float* __restrict__ cenT, const float* __restrict__ cen_b,
    const float* __restrict__ outT, const float* __restrict__ out_b,
    const float* __restrict__ ln_g, const float* __restrict__ ln_b,
    float* __restrict__ h_out,
    float* __restrict__ qw, __half* __restrict__ kxw, __half* __restrict__ vxw,
    const float* __restrict__ wqT, const float* __restrict__ wkT, const float* __restrict__ wvT)
{
    int tid = threadIdx.x;
    int g = tid >> 7;                 // local node 0/1
    int o = tid & 127;
    int bn = blockIdx.x * 2 + g;
    int b = bn / cN;
    int hh = o >> 5, c = o & 31;
    int srcb = (hh & 1) * 32;

    __shared__ float w_s[2][cK][2][32];   // 24 KB lerped weights; aliased as sh_c after pass 2
    __shared__ float sh_h[2][cH];
    __shared__ float sh_t[2][cH];
    __shared__ float sh_qk[2][cK * cHeads];
    __shared__ int   sh_nb[2][cK];
    __shared__ int   sh_idx[2][cK];
    __shared__ float sh_frac[2][cK];
    __shared__ float red[2][4];
    float* w_flat = &w_s[0][0][0][0];
    // sh_c[gr][node][o] partial buffer aliases the first 2048 floats of w_s
    #define SH_C(gr, node, oo) w_flat[(((gr) << 1) | (node)) * cH + (oo)]

    sh_h[g][o] = h_in[(size_t)bn * cH + o];
    float qv = qr[(size_t)bn * cH + o];
    if (o < cK) {
        sh_nb[g][o] = nbr[(size_t)bn * cK + o];
        float d = dist[(size_t)bn * cK + o];
        float z = d * TAB_INV;
        int idx = (int)z;
        if (idx > TABN - 2) idx = TABN - 2;
        sh_idx[g][o] = idx;
        sh_frac[g][o] = fminf(z - (float)idx, 1.0f);
    }
    __syncthreads();   // A

    // qt[h,c] = sum_k q[h,k]*wkl[k,c]  (wkl bias cancels in softmax)
    const float* wklp = wkl_w + l * 1024;
    float qt = 0.f;
    #pragma unroll 8
    for (int k = 0; k < 32; k++) qt += __shfl(qv, srcb + k) * wklp[k * 32 + c];

    // cooperative stage of lerped w_k/w_v into LDS (4x head-group dedup).
    // e = slot*64 + c2, slot = g*48+m, c2 = side*32+c; within a wave slot is
    // uniform -> each tab load is a coalesced 256B line pair.
    const float* tabl = tab + (size_t)l * TABN * 64;
    #pragma unroll 4
    for (int e = tid; e < 2 * cK * 64; e += 256) {
        int c2 = e & 63;
        int slot = e >> 6;           // 0..95
        int gg = slot >= cK;
        int m = slot - (gg ? cK : 0);
        int idx = sh_idx[gg][m];
        float f = sh_frac[gg][m];
        const float* tp = tabl + (size_t)idx * 64 + c2;
        float lo = tp[0], hi = tp[64];
        w_flat[e] = lo + f * (hi - lo);
    }
    __syncthreads();   // B

    const __half* kxb = kxr + (size_t)b * cN * cH;
    const __half* vxb = vxr + (size_t)b * cN * cH;

    // pass 1: logits (w_k from LDS), two edges per butterfly
    #pragma unroll 4
    for (int m = 0; m < cK; m += 2) {
        int j0 = sh_nb[g][m], j1 = sh_nb[g][m + 1];
        float k0 = __half2float(kxb[(size_t)j0 * cH + o]);
        float k1 = __half2float(kxb[(size_t)j1 * cH + o]);
        float w0 = w_s[g][m][0][c];
        float w1 = w_s[g][m + 1][0][c];
        float pa = qt * w0 * k0;
        float pb = qt * w1 * k1;
        float x = (c & 1) ? pb : pa;
        float y = (c & 1) ? pa : pb;
        x += __shfl_xor(y, 1);
        x += __shfl_xor(x, 2);
        x += __shfl_xor(x, 4);
        x += __shfl_xor(x, 8);
        x += __shfl_xor(x, 16);
        if (c < 2) sh_qk[g][(m + c) * cHeads + hh] = x;
    }
    __syncthreads();   // C

    // softmax over m per head
    {
        float v1 = sh_qk[g][c * cHeads + hh];
        float v2 = (c < cK - 32) ? sh_qk[g][(32 + c) * cHeads + hh] : -1e30f;
        float mx = fmaxf(v1, v2);
        #pragma unroll
        for (int off = 16; off; off >>= 1) mx = fmaxf(mx, __shfl_xor(mx, off));
        float e1 = __expf(v1 - mx);
        float e2 = (c < cK - 32) ? __expf(v2 - mx) : 0.f;
        float s = e1 + e2;
        #pragma unroll
        for (int off = 16; off; off >>= 1) s += __shfl_xor(s, off);
        float inv = 1.0f / s;
        sh_qk[g][c * cHeads + hh] = e1 * inv;
        if (c < cK - 32) sh_qk[g][(32 + c) * cHeads + hh] = e2 * inv;
    }
    __syncthreads();   // D

    // pass 2: t[h,c] = sum_m alpha*w_v*vx ; w_v from LDS, dual accumulators
    float t0 = 0.f, t1 = 0.f;
    #pragma unroll 4
    for (int m = 0; m < cK; m += 2) {
        int j0 = sh_nb[g][m], j1 = sh_nb[g][m + 1];
        float v0 = __half2float(vxb[(size_t)j0 * cH + o]);
        float v1 = __half2float(vxb[(size_t)j1 * cH + o]);
        t0 += sh_qk[g][m * cHeads + hh] * (w_s[g][m][1][c] * v0);
        t1 += sh_qk[g][(m + 1) * cHeads + hh] * (w_s[g][m + 1][1][c] * v1);
    }
    sh_t[g][o] = t0 + t1;
    __syncthreads();   // E  (w_s dead from here; sh_c alias live)

    // aggr (wvl, i split 16/16 across g) + cen (i split 64/64) -> partials for BOTH nodes
    const float* wvlTp = wvlT + l * 1024;
    float xp0 = 0.f, xp1 = 0.f;
    #pragma unroll
    for (int i = g * 16; i < g * 16 + 16; i++) {
        float w = wvlTp[i * 32 + c];
        xp0 += w * sh_t[0][hh * 32 + i];
        xp1 += w * sh_t[1][hh * 32 + i];
    }
    const float* cenTp = cenT + (size_t)l * cH * cH;
    #pragma unroll 4
    for (int i = g * 64; i < g * 64 + 64; i++) {
        float w = cenTp[i * cH + o];
        xp0 += w * sh_h[0][i];
        xp1 += w * sh_h[1][i];
    }
    SH_C(g, 0, o) = xp0;
    SH_C(g, 1, o) = xp1;
    __syncthreads();   // F
    float x = SH_C(0, g, o) + SH_C(1, g, o) + cen_b[l * cH + o] + wvl_b[l * 32 + c];

    // LayerNorm
    float s1 = x, s2 = x * x;
    #pragma unroll
    for (int off = 32; off; off >>= 1) {
        s1 += __shfl_xor(s1, off);
        s2 += __shfl_xor(s2, off);
    }
    int wid = (o >> 6);
    if ((o & 63) == 0) { red[g][wid * 2] = s1; red[g][wid * 2 + 1] = s2; }
    __syncthreads();   // G
    float tot1 = red[g][0] + red[g][2], tot2 = red[g][1] + red[g][3];
    float mu = tot1 * (1.0f / 128.0f);
    float var = tot2 * (1.0f / 128.0f) - mu * mu;
    float xn = (x - mu) * rsqrtf(var + 1e-5f);
    xn = xn * ln_g[l * cH + o] + ln_b[l * cH + o];
    float sx = sspf(xn);
    sh_t[g][o] = sx;   // safe: all sh_t readers passed barrier F
    __syncthreads();   // H

    // out matmul (i split 64/64 across g, weights shared for both nodes)
    const float* outTp = outT + (size_t)l * cH * cH;
    float op0 = 0.f, op1 = 0.f;
    #pragma unroll 4
    for (int i = g * 64; i < g * 64 + 64; i++) {
        float w = outTp[i * cH + o];
        op0 += w * sh_t[0][i];
        op1 += w * sh_t[1][i];
    }
    SH_C(g, 0, o) = op0;   // safe: sh_c last read before barrier G
    SH_C(g, 1, o) = op1;
    __syncthreads();   // I
    float hnew = sh_h[g][o] + out_b[l * cH + o] + SH_C(0, g, o) + SH_C(1, g, o);
    h_out[(size_t)bn * cH + o] = hnew;

    // ---- fused qkv for layer l+1 (unchanged from round-0) ----
    if (l < cL - 1) {
        size_t wo = ((size_t)(l + 1) * 4 + hh) * 1024;
        const float* bq = wqT + wo;
        const float* bk = wkT + wo;
        const float* bv = wvT + wo;
        float sq = 0.f, sk = 0.f, sv = 0.f;
        #pragma unroll
        for (int d = 0; d < 32; d++) {
            float xv = __shfl(hnew, srcb + d);
            sq += bq[d * 32 + c] * xv;
            sk += bk[d * 32 + c] * xv;
            sv += bv[d * 32 + c] * xv;
        }
        qw[(size_t)bn * cH + o] = sq;
        kxw[(size_t)bn * cH + o] = __float2half(sk);
        vxw[(size_t)bn * cH + o] = __float2half(sv);
    }
    #undef SH_C
}

// ---------------- FC head ----------------
__global__ void __launch_bounds__(256) k_fc1p(const float* __restrict__ hbuf,
                                              const float* __restrict__ w,
                                              float* __restrict__ partial)
{
    int o = blockIdx.x >> 2, qp = blockIdx.x & 3;
    int tid = threadIdx.x;
    constexpr int CH = cFLAT / 4;
    const float4* wr = (const float4*)(w + (size_t)o * cFLAT + qp * CH);
    float a[4] = {0.f, 0.f, 0.f, 0.f};
    for (int i = tid; i < CH / 4; i += 256) {
        float4 wv = wr[i];
        #pragma unroll
        for (int bb = 0; bb < 4; bb++) {
            float4 hv = ((const float4*)(hbuf + (size_t)bb * cFLAT + qp * CH))[i];
            a[bb] += wv.x * hv.x + wv.y * hv.y + wv.z * hv.z + wv.w * hv.w;
        }
    }
    #pragma unroll
    for (int off = 32; off; off >>= 1) {
        #pragma unroll
        for (int bb = 0; bb < 4; bb++) a[bb] += __shfl_xor(a[bb], off);
    }
    __shared__ float red[4][4];
    if ((tid & 63) == 0) {
        #pragma unroll
        for (int bb = 0; bb < 4; bb++) red[tid >> 6][bb] = a[bb];
    }
    __syncthreads();
    if (tid < 4) {
        float s = red[0][tid] + red[1][tid] + red[2][tid] + red[3][tid];
        partial[((size_t)o * 4 + qp) * 4 + tid] = s;
    }
}

__global__ void __launch_bounds__(512) k_head2(const float* __restrict__ partial,
                                               const float* __restrict__ fc1_b,
                                               const float* __restrict__ fc2_w,
                                               const float* __restrict__ fc2_b,
                                               const float* __restrict__ fc3_w,
                                               const float* __restrict__ fc3_b,
                                               float* __restrict__ out)
{
    int tid = threadIdx.x;
    __shared__ float y1[4][128];
    __shared__ float y2[4][64];
    {
        int bb = tid >> 7, o = tid & 127;
        float s = fc1_b[o];
        #pragma unroll
        for (int qp = 0; qp < 4; qp++) s += partial[((size_t)o * 4 + qp) * 4 + bb];
        y1[bb][o] = fmaxf(s, 0.f);
    }
    __syncthreads();
    if (tid < 256) {
        int bb = tid >> 6, o = tid & 63;
        float s = fc2_b[o];
        #pragma unroll 8
        for (int i = 0; i < 128; i++) s += fc2_w[o * 128 + i] * y1[bb][i];
        y2[bb][o] = fmaxf(s, 0.f);
    }
    __syncthreads();
    if (tid < 4) {
        float s = fc3_b[0];
        #pragma unroll 8
        for (int i = 0; i < 64; i++) s += fc3_w[i] * y2[tid][i];
        out[tid] = s;
    }
}

extern "C" void kernel_launch(void* const* d_in, const int* in_sizes, int n_in,
                              void* d_out, int out_size, void* d_ws, size_t ws_size,
                              hipStream_t stream) {
    const float* state  = (const float*)d_in[0];
    const float* ppv    = (const float*)d_in[1];
    const float* w_prot = (const float*)d_in[2];
    const float* b_prot = (const float*)d_in[3];
    const float* w_lig  = (const float*)d_in[4];
    const float* b_lig  = (const float*)d_in[5];
    const float* wq     = (const float*)d_in[6];
    const float* wk     = (const float*)d_in[7];
    const float* wv     = (const float*)d_in[8];
    const float* wkn1_w = (const float*)d_in[9];
    const float* wkn1_b = (const float*)d_in[10];
    const float* wkn2_w = (const float*)d_in[11];
    const float* wkn2_b = (const float*)d_in[12];
    const float* wkl_w  = (const float*)d_in[13];
    const float* wvn1_w = (const float*)d_in[15];
    const float* wvn1_b = (const float*)d_in[16];
    const float* wvn2_w = (const float*)d_in[17];
    const float* wvn2_b = (const float*)d_in[18];
    const float* wvl_w  = (const float*)d_in[19];
    const float* wvl_b  = (const float*)d_in[20];
    const float* cen_w  = (const float*)d_in[21];
    const float* cen_b  = (const float*)d_in[22];
    const float* out_w  = (const float*)d_in[23];
    const float* out_b  = (const float*)d_in[24];
    const float* ln_g   = (const float*)d_in[25];
    const float* ln_b   = (const float*)d_in[26];
    const float* fc1_w  = (const float*)d_in[27];
    const float* fc1_b  = (const float*)d_in[28];
    const float* fc2_w  = (const float*)d_in[29];
    const float* fc2_b  = (const float*)d_in[30];
    const float* fc3_w  = (const float*)d_in[31];
    const float* fc3_b  = (const float*)d_in[32];

    float* ws = (float*)d_ws;
    size_t off = 0;
    float* pos   = ws + off; off += (size_t)cB * cN * 3;
    float* h_a   = ws + off; off += (size_t)cB * cN * cH;
    float* h_b   = ws + off; off += (size_t)cB * cN * cH;
    float* qA    = ws + off; off += (size_t)cB * cN * cH;
    float* qB    = ws + off; off += (size_t)cB * cN * cH;
    __half* kA   = (__half*)(ws + off); off += (size_t)cB * cN * cH / 2;
    __half* vA   = (__half*)(ws + off); off += (size_t)cB * cN * cH / 2;
    __half* kB   = (__half*)(ws + off); off += (size_t)cB * cN * cH / 2;
    __half* vB   = (__half*)(ws + off); off += (size_t)cB * cN * cH / 2;
    float* distb = ws + off; off += (size_t)cEdges;
    int*   nbrb  = (int*)(ws + off); off += (size_t)cEdges;
    float* tabb  = ws + off; off += (size_t)cL * TABN * 64;  // 1.57M
    float* wqT   = ws + off; off += 24576;
    float* wkT   = ws + off; off += 24576;
    float* wvT   = ws + off; off += 24576;
    float* w1Tk  = ws + off; off += 24576;
    float* w1Tv  = ws + off; off += 24576;
    float* w2Tk  = ws + off; off += 6144;
    float* w2Tv  = ws + off; off += 6144;
    float* wvlT  = ws + off; off += 6144;
    float* cenT  = ws + off; off += 98304;
    float* outT  = ws + off; off += 98304;
    float* partial = ws + off; off += 2048;

    k_init<<<2720, 256, 0, stream>>>(wq, wk, wv, wkn1_w, wvn1_w, wkn2_w, wvn2_w,
                                     wvl_w, cen_w, out_w,
                                     wqT, wkT, wvT, w1Tk, w1Tv, w2Tk, w2Tv, wvlT, cenT, outT,
                                     state, ppv, w_prot, b_prot, w_lig, b_lig, h_a, pos);
    k_knn<<<cN + TABN / 4 + cB * cN / 2, 256, 0, stream>>>(
        pos, nbrb, distb,
        w1Tk, wkn1_b, w2Tk, wkn2_b, w1Tv, wvn1_b, w2Tv, wvn2_b, tabb,
        h_a, wqT, wkT, wvT, qA, kA, vA);

    float* hc = h_a;
    float* hn = h_b;
    for (int l = 0; l < cL; l++) {
        float* qr = (l & 1) ? qB : qA;
        __half* kr = (l & 1) ? kB : kA;
        __half* vr = (l & 1) ? vB : vA;
        float* qw2 = (l & 1) ? qA : qB;
        __half* kw2 = (l & 1) ? kA : kB;
        __half* vw2 = (l & 1) ? vA : vB;
        k_attn<<<cB * cN / 2, 256, 0, stream>>>(l, hc, qr, kr, vr, nbrb, distb, tabb,
            wkl_w, wvlT, wvl_b, cenT, cen_b, outT, out_b, ln_g, ln_b,
            hn, qw2, kw2, vw2, wqT, wkT, wvT);
        float* tmp = hc; hc = hn; hn = tmp;
    }

    k_fc1p<<<512, 256, 0, stream>>>(hc, fc1_w, partial);
    k_head2<<<1, 512, 0, stream>>>(partial, fc1_b, fc2_w, fc2_b, fc3_w, fc3_b, (float*)d_out);
}

// Round 5
// 310.892 us; speedup vs baseline: 1.3139x; 1.2430x over previous
//
#include <hip/hip_runtime.h>
#include <hip/hip_fp16.h>
#include <math.h>

constexpr int cB   = 4;
constexpr int cNL  = 150;
constexpr int cNP  = 550;
constexpr int cN   = 700;
constexpr int cH   = 128;
constexpr int cHeads = 4;
constexpr int cL   = 6;
constexpr int cK   = 48;
constexpr int cPF  = 27;
constexpr int cNC  = 13;
constexpr int cFLAT = cN * cH;       // 89600
constexpr int cEdges = cB * cN * cK; // 134400

constexpr int   TABN = 4096;
#define TAB_DMAX 11.0f
#define TAB_HT   (TAB_DMAX / (float)(TABN - 1))
#define TAB_INV  ((float)(TABN - 1) / TAB_DMAX)

#define RBF_STEP (10.0f / 127.0f)
#define RBF_COEFF (-0.5f / (RBF_STEP * RBF_STEP))
#define LOG2F_C 0.69314718055994530942f

__device__ __forceinline__ float sspf(float x) {
    float ax = fabsf(x);
    return fmaxf(x, 0.0f) + __logf(1.0f + __expf(-ax)) - LOG2F_C;
}

__device__ __forceinline__ int mbcnt64(unsigned long long m) {
    return __builtin_amdgcn_mbcnt_hi((unsigned)(m >> 32),
           __builtin_amdgcn_mbcnt_lo((unsigned)m, 0));
}

// ---------------- fused: weight transposes + embedding ----------------
__global__ void __launch_bounds__(256) k_init(
    const float* __restrict__ wq, const float* __restrict__ wk, const float* __restrict__ wv,
    const float* __restrict__ wkn1_w, const float* __restrict__ wvn1_w,
    const float* __restrict__ wkn2_w, const float* __restrict__ wvn2_w,
    const float* __restrict__ wvl_w,
    const float* __restrict__ cen_w, const float* __restrict__ out_w,
    float* __restrict__ wqT, float* __restrict__ wkT, float* __restrict__ wvT,
    float* __restrict__ w1Tk, float* __restrict__ w1Tv,
    float* __restrict__ w2Tk, float* __restrict__ w2Tv,
    float* __restrict__ wvlT,
    float* __restrict__ cenT, float* __restrict__ outT,
    const float* __restrict__ state, const float* __restrict__ ppv,
    const float* __restrict__ w_prot, const float* __restrict__ b_prot,
    const float* __restrict__ w_lig, const float* __restrict__ b_lig,
    float* __restrict__ h, float* __restrict__ pos)
{
    if (blockIdx.x < 1320) {
        int idx = blockIdx.x * 256 + threadIdx.x;
        if (idx < 3 * 24576) {
            int seg = idx / 24576, i = idx % 24576;
            const float* src = seg == 0 ? wq : (seg == 1 ? wk : wv);
            float* dst = seg == 0 ? wqT : (seg == 1 ? wkT : wvT);
            int l = i / 4096, r = i % 4096;
            int hh = r / 1024, r2 = r % 1024;
            int d = r2 / 32, k = r2 % 32;
            dst[i] = src[(((size_t)l * 4 + hh) * 32 + k) * 32 + d];
            return;
        }
        idx -= 3 * 24576;
        if (idx < 2 * 24576) {
            int seg = idx / 24576, i = idx % 24576;
            const float* src = seg == 0 ? wkn1_w : wvn1_w;
            float* dst = seg == 0 ? w1Tk : w1Tv;
            int l = i / 4096, r = i % 4096;
            int c = r / 32, o = r % 32;
            dst[i] = src[((size_t)l * 32 + o) * 128 + c];
            return;
        }
        idx -= 2 * 24576;
        if (idx < 3 * 6144) {
            int seg = idx / 6144, i = idx % 6144;
            const float* src = seg == 0 ? wkn2_w : (seg == 1 ? wvn2_w : wvl_w);
            float* dst = seg == 0 ? w2Tk : (seg == 1 ? w2Tv : wvlT);
            int l = i / 1024, r = i % 1024;
            int c = r / 32, o = r % 32;
            dst[i] = src[((size_t)l * 32 + o) * 32 + c];
            return;
        }
        idx -= 3 * 6144;
        int seg = idx / 98304, i = idx % 98304;
        const float* src = seg == 0 ? cen_w : out_w;
        float* dst = seg == 0 ? cenT : outT;
        int l = i / 16384, r = i % 16384;
        int ii = r / 128, o = r % 128;
        dst[i] = src[((size_t)l * 128 + o) * 128 + ii];
        return;
    }
    // ---- embed: 2 nodes per block ----
    int rel = blockIdx.x - 1320;
    int node = rel * 2 + (threadIdx.x >> 7);
    int b = node / cN, n = node % cN;
    int o = threadIdx.x & 127;
    int lane = threadIdx.x & 63;
    float out;
    if (n < cNP) {
        const float* src = ppv + ((size_t)b * cNP + n) * 30;
        float v = (lane < 30) ? src[lane] : 0.f;
        float s = b_prot[o];
        #pragma unroll
        for (int f = 0; f < cPF; f++) s += w_prot[o * cPF + f] * __shfl(v, 3 + f);
        out = s;
        if (o < 3) pos[((size_t)b * cN + n) * 3 + o] = v;
    } else {
        int nl = n - cNP;
        const float* src = state + ((size_t)b * cNL + nl) * 4;
        float v = (lane < 4) ? src[lane] : 0.f;
        int t = (int)__shfl(v, 3);
        out = w_lig[o * cNC + t] + b_lig[o];
        if (o < 3) pos[((size_t)b * cN + n) * 3 + o] = v;
    }
    h[((size_t)b * cN + n) * cH + o] = out;
}

// ---------------- KNN (radix-select) + edge-MLP table build (lerp-pair float2) + qkv(l=0) ----------------
__global__ void __launch_bounds__(256) k_knn(
    const float* __restrict__ pos, int* __restrict__ nbr, float* __restrict__ dist,
    const float* __restrict__ w1Tk, const float* __restrict__ wkn1_b,
    const float* __restrict__ w2Tk, const float* __restrict__ wkn2_b,
    const float* __restrict__ w1Tv, const float* __restrict__ wvn1_b,
    const float* __restrict__ w2Tv, const float* __restrict__ wvn2_b,
    float* __restrict__ tabP,
    const float* __restrict__ hbuf,
    const float* __restrict__ wqT, const float* __restrict__ wkT, const float* __restrict__ wvT,
    float* __restrict__ q0, __half* __restrict__ kx0, __half* __restrict__ vx0)
{
    int tid = threadIdx.x;
    if (blockIdx.x < cN) {
        // ---- knn: one wave per node, radix-select on float bit patterns ----
        int lane = tid & 63;
        int node = blockIdx.x * 4 + (tid >> 6);
        int b = node / cN, n = node % cN;
        const float* pb = pos + (size_t)b * cN * 3;
        float px = pb[n * 3 + 0], py = pb[n * 3 + 1], pz = pb[n * 3 + 2];
        float d2v[11];
        #pragma unroll
        for (int s = 0; s < 11; s++) {
            int j = lane + s * 64;
            float d2 = 1e30f;
            if (j < cN) {
                float dx = pb[j * 3 + 0] - px;
                float dy = pb[j * 3 + 1] - py;
                float dz = pb[j * 3 + 2] - pz;
                d2 = dx * dx + dy * dy + dz * dz;
                if (j == n) d2 = 1e9f;
            }
            d2v[s] = d2;
        }
        unsigned p = 0;
        for (int bit = 30; bit >= 0; --bit) {
            unsigned t = p | (1u << bit);
            int cnt = 0;
            #pragma unroll
            for (int s = 0; s < 11; s++)
                cnt += __popcll(__ballot(__float_as_uint(d2v[s]) < t));
            if (cnt <= 47) p = t;
        }
        int c_lt = 0;
        #pragma unroll
        for (int s = 0; s < 11; s++)
            c_lt += __popcll(__ballot(__float_as_uint(d2v[s]) < p));
        int base = 0, ebase = c_lt, need = 48 - c_lt;
        #pragma unroll
        for (int s = 0; s < 11; s++) {
            unsigned u = __float_as_uint(d2v[s]);
            unsigned long long blt = __ballot(u < p);
            unsigned long long beq = __ballot(u == p);
            int posn = -1;
            int bl = mbcnt64(blt);
            if (u < p) posn = base + bl;
            base += __popcll(blt);
            int r = mbcnt64(beq);
            int cs = __popcll(beq);
            int take = need < cs ? need : cs;
            if (u == p && r < take) posn = ebase + r;
            ebase += take; need -= take;
            if (posn >= 0) {
                nbr[(size_t)node * cK + posn] = s * 64 + lane;
                dist[(size_t)node * cK + posn] = sqrtf(d2v[s]);
            }
        }
        return;
    }
    if (blockIdx.x < cN + TABN / 4) {
        // ---- table build: wave per entry; lerp-pair layout:
        // float2 slot [(l*TABN+e)*2+side][c] = { val[e], val[e+1] }
        int rel = blockIdx.x - cN;
        int lane = tid & 63;
        int e = rel * 4 + (tid >> 6);
        int side = lane >> 5, o = lane & 31;
        float d = (float)e * TAB_HT;
        float z = d * (127.0f / 10.0f);
        int c0 = (int)floorf(z) - 7;
        c0 = c0 < 0 ? 0 : (c0 > 112 ? 112 : c0);
        int i = lane & 15;
        float tt = d - RBF_STEP * (float)(c0 + i);
        float eav = __expf(RBF_COEFF * tt * tt);
        const float* w1T = (side ? w1Tv : w1Tk);
        const float* b1  = (side ? wvn1_b : wkn1_b);
        const float* w2T = (side ? w2Tv : w2Tk);
        const float* b2  = (side ? wvn2_b : wkn2_b);
        int srcb = side * 32;
        for (int l = 0; l < cL; l++) {
            float s = b1[l * 32 + o];
            const float* w1p = w1T + (size_t)l * 4096;
            #pragma unroll
            for (int ii = 0; ii < 16; ii++)
                s += w1p[(c0 + ii) * 32 + o] * __shfl(eav, ii);
            float t1 = sspf(s);
            float s2 = b2[l * 32 + o];
            const float* w2p = w2T + (size_t)l * 1024;
            #pragma unroll
            for (int cc = 0; cc < 32; cc++)
                s2 += w2p[cc * 32 + o] * __shfl(t1, srcb + cc);
            tabP[((((size_t)l * TABN + e) * 2 + side) * 32 + o) * 2] = s2;
            if (e > 0)
                tabP[((((size_t)l * TABN + (e - 1)) * 2 + side) * 32 + o) * 2 + 1] = s2;
        }
        return;
    }
    // ---- qkv for layer 0: 2 nodes per block ----
    int bn = (blockIdx.x - cN - TABN / 4) * 2 + (tid >> 7);
    int o = tid & 127;
    int hh = o >> 5, kq = o & 31;
    float hval = hbuf[(size_t)bn * cH + o];
    size_t wo = ((size_t)0 * 4 + hh) * 1024;
    const float* bq = wqT + wo;
    const float* bk = wkT + wo;
    const float* bv = wvT + wo;
    int srcb = (hh & 1) * 32;
    float sq = 0.f, sk = 0.f, sv = 0.f;
    #pragma unroll
    for (int d = 0; d < 32; d++) {
        float x = __shfl(hval, srcb + d);
        sq += bq[d * 32 + kq] * x;
        sk += bk[d * 32 + kq] * x;
        sv += bv[d * 32 + kq] * x;
    }
    q0[(size_t)bn * cH + o] = sq;
    kx0[(size_t)bn * cH + o] = __float2half(sk);
    vx0[(size_t)bn * cH + o] = __float2half(sv);
}

// ---------------- fused attention + LN + residual MLP + next-layer qkv ----------------
// Round-0 structure (2 nodes / 256T). Tab lerps use float2 pair layout + in-wave
// half-split dedup: lane<32 lerps edge m, lane>=32 lerps edge m+1, one shfl_xor(32)
// exchanges the lerped scalars. 192 tab loads/thread -> 48.
__global__ void __launch_bounds__(256) k_attn(
    int l,
    const float* __restrict__ h_in, const float* __restrict__ qr,
    const __half* __restrict__ kxr, const __half* __restrict__ vxr,
    const int* __restrict__ nbr, const float* __restrict__ dist,
    const float* __restrict__ tabP,
    const float* __restrict__ wkl_w,
    const float* __restrict__ wvlT, const float* __restrict__ wvl_b,
    const float* __restrict__ cenT, const float* __restrict__ cen_b,
    const float* __restrict__ outT, const float* __restrict__ out_b,
    const float* __restrict__ ln_g, const float* __restrict__ ln_b,
    float* __restrict__ h_out,
    float* __restrict__ qw, __half* __restrict__ kxw, __half* __restrict__ vxw,
    const float* __restrict__ wqT, const float* __restrict__ wkT, const float* __restrict__ wvT)
{
    int tid = threadIdx.x;
    int g = tid >> 7;                 // local node 0/1
    int o = tid & 127;
    int lane = tid & 63;
    int bn = blockIdx.x * 2 + g;
    int b = bn / cN;
    int hh = o >> 5, c = o & 31;
    int srcb = (hh & 1) * 32;
    int hi = lane >> 5;               // 0: lower half-wave, 1: upper

    __shared__ float sh_h[2][cH];
    __shared__ float sh_qk[2][cK * cHeads];
    __shared__ float sh_t[2][cH];
    __shared__ int   sh_nb[2][cK];
    __shared__ int   sh_idx[2][cK];
    __shared__ float sh_frac[2][cK];
    __shared__ float red[2][4];

    sh_h[g][o] = h_in[(size_t)bn * cH + o];
    float qv = qr[(size_t)bn * cH + o];
    if (o < cK) {
        sh_nb[g][o] = nbr[(size_t)bn * cK + o];
        float d = dist[(size_t)bn * cK + o];
        float z = d * TAB_INV;
        int idx = (int)z;
        if (idx > TABN - 2) idx = TABN - 2;
        sh_idx[g][o] = idx;
        sh_frac[g][o] = fminf(z - (float)idx, 1.0f);
    }
    __syncthreads();

    // qt[h,c] = sum_k q[h,k]*wkl[k,c]  (wkl bias cancels in softmax)
    const float* wklp = wkl_w + l * 1024;
    float qt = 0.f;
    #pragma unroll 8
    for (int k = 0; k < 32; k++) qt += __shfl(qv, srcb + k) * wklp[k * 32 + c];

    const __half* kxb = kxr + (size_t)b * cN * cH;
    const __half* vxb = vxr + (size_t)b * cN * cH;
    const float2* tab2 = (const float2*)tabP + (size_t)l * TABN * 64;

    // pass 1: logits, half-split lerp-pair w_k, two edges per butterfly
    #pragma unroll 4
    for (int m = 0; m < cK; m += 2) {
        int j0 = sh_nb[g][m], j1 = sh_nb[g][m + 1];
        float k0 = __half2float(kxb[(size_t)j0 * cH + o]);
        float k1 = __half2float(kxb[(size_t)j1 * cH + o]);
        int mm = m + hi;
        float2 tp = tab2[((size_t)sh_idx[g][mm] * 2 + 0) * 32 + c];
        float wmine = tp.x + sh_frac[g][mm] * (tp.y - tp.x);
        float wother = __shfl_xor(wmine, 32);
        float w0 = hi ? wother : wmine;
        float w1 = hi ? wmine : wother;
        float pa = qt * w0 * k0;
        float pb = qt * w1 * k1;
        float x = (c & 1) ? pb : pa;
        float y = (c & 1) ? pa : pb;
        x += __shfl_xor(y, 1);
        x += __shfl_xor(x, 2);
        x += __shfl_xor(x, 4);
        x += __shfl_xor(x, 8);
        x += __shfl_xor(x, 16);
        if (c < 2) sh_qk[g][(m + c) * cHeads + hh] = x;
    }
    __syncthreads();

    // softmax over m per head
    {
        float v1 = sh_qk[g][c * cHeads + hh];
        float v2 = (c < cK - 32) ? sh_qk[g][(32 + c) * cHeads + hh] : -1e30f;
        float mx = fmaxf(v1, v2);
        #pragma unroll
        for (int off = 16; off; off >>= 1) mx = fmaxf(mx, __shfl_xor(mx, off));
        float e1 = __expf(v1 - mx);
        float e2 = (c < cK - 32) ? __expf(v2 - mx) : 0.f;
        float s = e1 + e2;
        #pragma unroll
        for (int off = 16; off; off >>= 1) s += __shfl_xor(s, off);
        float inv = 1.0f / s;
        sh_qk[g][c * cHeads + hh] = e1 * inv;
        if (c < cK - 32) sh_qk[g][(32 + c) * cHeads + hh] = e2 * inv;
    }
    __syncthreads();

    // pass 2: t[h,c] = sum_m alpha*w_v*vx ; half-split lerp-pair w_v, dual accumulators
    float t0 = 0.f, t1 = 0.f;
    #pragma unroll 4
    for (int m = 0; m < cK; m += 2) {
        int j0 = sh_nb[g][m], j1 = sh_nb[g][m + 1];
        float v0 = __half2float(vxb[(size_t)j0 * cH + o]);
        float v1 = __half2float(vxb[(size_t)j1 * cH + o]);
        int mm = m + hi;
        float2 sp = tab2[((size_t)sh_idx[g][mm] * 2 + 1) * 32 + c];
        float wmine = sp.x + sh_frac[g][mm] * (sp.y - sp.x);
        float wother = __shfl_xor(wmine, 32);
        float w0 = hi ? wother : wmine;
        float w1 = hi ? wmine : wother;
        t0 += sh_qk[g][m * cHeads + hh] * (w0 * v0);
        t1 += sh_qk[g][(m + 1) * cHeads + hh] * (w1 * v1);
    }
    sh_t[g][o] = t0 + t1;
    __syncthreads();

    const float* wvlTp = wvlT + l * 1024;
    float aggr = wvl_b[l * 32 + c];
    #pragma unroll 8
    for (int i = 0; i < 32; i++) aggr += wvlTp[i * 32 + c] * sh_t[g][hh * 32 + i];

    const float* cenTp = cenT + (size_t)l * cH * cH;
    float x0 = 0.f, x1 = 0.f;
    #pragma unroll 4
    for (int i = 0; i < cH; i += 2) {
        x0 += cenTp[i * cH + o] * sh_h[g][i];
        x1 += cenTp[(i + 1) * cH + o] * sh_h[g][i + 1];
    }
    float x = cen_b[l * cH + o] + aggr + x0 + x1;

    // LayerNorm
    float s1 = x, s2 = x * x;
    #pragma unroll
    for (int off = 32; off; off >>= 1) {
        s1 += __shfl_xor(s1, off);
        s2 += __shfl_xor(s2, off);
    }
    int wid = (o >> 6);
    if ((o & 63) == 0) { red[g][wid * 2] = s1; red[g][wid * 2 + 1] = s2; }
    __syncthreads();
    float tot1 = red[g][0] + red[g][2], tot2 = red[g][1] + red[g][3];
    float mu = tot1 * (1.0f / 128.0f);
    float var = tot2 * (1.0f / 128.0f) - mu * mu;
    float xn = (x - mu) * rsqrtf(var + 1e-5f);
    xn = xn * ln_g[l * cH + o] + ln_b[l * cH + o];
    float sx = sspf(xn);
    sh_t[g][o] = sx;   // safe: all sh_t readers passed the sync above
    __syncthreads();

    const float* outTp = outT + (size_t)l * cH * cH;
    float o0 = 0.f, o1 = 0.f;
    #pragma unroll 4
    for (int i = 0; i < cH; i += 2) {
        o0 += outTp[i * cH + o] * sh_t[g][i];
        o1 += outTp[(i + 1) * cH + o] * sh_t[g][i + 1];
    }
    float hnew = sh_h[g][o] + out_b[l * cH + o] + o0 + o1;
    h_out[(size_t)bn * cH + o] = hnew;

    // ---- fused qkv for layer l+1 (writes the other buffer set) ----
    if (l < cL - 1) {
        size_t wo = ((size_t)(l + 1) * 4 + hh) * 1024;
        const float* bq = wqT + wo;
        const float* bk = wkT + wo;
        const float* bv = wvT + wo;
        float sq = 0.f, sk = 0.f, sv = 0.f;
        #pragma unroll
        for (int d = 0; d < 32; d++) {
            float xv = __shfl(hnew, srcb + d);
            sq += bq[d * 32 + c] * xv;
            sk += bk[d * 32 + c] * xv;
            sv += bv[d * 32 + c] * xv;
        }
        qw[(size_t)bn * cH + o] = sq;
        kxw[(size_t)bn * cH + o] = __float2half(sk);
        vxw[(size_t)bn * cH + o] = __float2half(sv);
    }
}

// ---------------- FC head ----------------
__global__ void __launch_bounds__(256) k_fc1p(const float* __restrict__ hbuf,
                                              const float* __restrict__ w,
                                              float* __restrict__ partial)
{
    int o = blockIdx.x >> 2, qp = blockIdx.x & 3;
    int tid = threadIdx.x;
    constexpr int CH = cFLAT / 4;
    const float4* wr = (const float4*)(w + (size_t)o * cFLAT + qp * CH);
    float a[4] = {0.f, 0.f, 0.f, 0.f};
    for (int i = tid; i < CH / 4; i += 256) {
        float4 wv = wr[i];
        #pragma unroll
        for (int bb = 0; bb < 4; bb++) {
            float4 hv = ((const float4*)(hbuf + (size_t)bb * cFLAT + qp * CH))[i];
            a[bb] += wv.x * hv.x + wv.y * hv.y + wv.z * hv.z + wv.w * hv.w;
        }
    }
    #pragma unroll
    for (int off = 32; off; off >>= 1) {
        #pragma unroll
        for (int bb = 0; bb < 4; bb++) a[bb] += __shfl_xor(a[bb], off);
    }
    __shared__ float red[4][4];
    if ((tid & 63) == 0) {
        #pragma unroll
        for (int bb = 0; bb < 4; bb++) red[tid >> 6][bb] = a[bb];
    }
    __syncthreads();
    if (tid < 4) {
        float s = red[0][tid] + red[1][tid] + red[2][tid] + red[3][tid];
        partial[((size_t)o * 4 + qp) * 4 + tid] = s;
    }
}

__global__ void __launch_bounds__(512) k_head2(const float* __restrict__ partial,
                                               const float* __restrict__ fc1_b,
                                               const float* __restrict__ fc2_w,
                                               const float* __restrict__ fc2_b,
                                               const float* __restrict__ fc3_w,
                                               const float* __restrict__ fc3_b,
                                               float* __restrict__ out)
{
    int tid = threadIdx.x;
    __shared__ float y1[4][128];
    __shared__ float y2[4][64];
    {
        int bb = tid >> 7, o = tid & 127;
        float s = fc1_b[o];
        #pragma unroll
        for (int qp = 0; qp < 4; qp++) s += partial[((size_t)o * 4 + qp) * 4 + bb];
        y1[bb][o] = fmaxf(s, 0.f);
    }
    __syncthreads();
    if (tid < 256) {
        int bb = tid >> 6, o = tid & 63;
        float s = fc2_b[o];
        #pragma unroll 8
        for (int i = 0; i < 128; i++) s += fc2_w[o * 128 + i] * y1[bb][i];
        y2[bb][o] = fmaxf(s, 0.f);
    }
    __syncthreads();
    if (tid < 4) {
        float s = fc3_b[0];
        #pragma unroll 8
        for (int i = 0; i < 64; i++) s += fc3_w[i] * y2[tid][i];
        out[tid] = s;
    }
}

extern "C" void kernel_launch(void* const* d_in, const int* in_sizes, int n_in,
                              void* d_out, int out_size, void* d_ws, size_t ws_size,
                              hipStream_t stream) {
    const float* state  = (const float*)d_in[0];
    const float* ppv    = (const float*)d_in[1];
    const float* w_prot = (const float*)d_in[2];
    const float* b_prot = (const float*)d_in[3];
    const float* w_lig  = (const float*)d_in[4];
    const float* b_lig  = (const float*)d_in[5];
    const float* wq     = (const float*)d_in[6];
    const float* wk     = (const float*)d_in[7];
    const float* wv     = (const float*)d_in[8];
    const float* wkn1_w = (const float*)d_in[9];
    const float* wkn1_b = (const float*)d_in[10];
    const float* wkn2_w = (const float*)d_in[11];
    const float* wkn2_b = (const float*)d_in[12];
    const float* wkl_w  = (const float*)d_in[13];
    const float* wvn1_w = (const float*)d_in[15];
    const float* wvn1_b = (const float*)d_in[16];
    const float* wvn2_w = (const float*)d_in[17];
    const float* wvn2_b = (const float*)d_in[18];
    const float* wvl_w  = (const float*)d_in[19];
    const float* wvl_b  = (const float*)d_in[20];
    const float* cen_w  = (const float*)d_in[21];
    const float* cen_b  = (const float*)d_in[22];
    const float* out_w  = (const float*)d_in[23];
    const float* out_b  = (const float*)d_in[24];
    const float* ln_g   = (const float*)d_in[25];
    const float* ln_b   = (const float*)d_in[26];
    const float* fc1_w  = (const float*)d_in[27];
    const float* fc1_b  = (const float*)d_in[28];
    const float* fc2_w  = (const float*)d_in[29];
    const float* fc2_b  = (const float*)d_in[30];
    const float* fc3_w  = (const float*)d_in[31];
    const float* fc3_b  = (const float*)d_in[32];

    float* ws = (float*)d_ws;
    size_t off = 0;
    float* pos   = ws + off; off += (size_t)cB * cN * 3;
    float* h_a   = ws + off; off += (size_t)cB * cN * cH;
    float* h_b   = ws + off; off += (size_t)cB * cN * cH;
    float* qA    = ws + off; off += (size_t)cB * cN * cH;
    float* qB    = ws + off; off += (size_t)cB * cN * cH;
    __half* kA   = (__half*)(ws + off); off += (size_t)cB * cN * cH / 2;
    __half* vA   = (__half*)(ws + off); off += (size_t)cB * cN * cH / 2;
    __half* kB   = (__half*)(ws + off); off += (size_t)cB * cN * cH / 2;
    __half* vB   = (__half*)(ws + off); off += (size_t)cB * cN * cH / 2;
    float* distb = ws + off; off += (size_t)cEdges;
    int*   nbrb  = (int*)(ws + off); off += (size_t)cEdges;
    float* tabb  = ws + off; off += (size_t)cL * TABN * 64 * 2;  // lerp-pair float2
    float* wqT   = ws + off; off += 24576;
    float* wkT   = ws + off; off += 24576;
    float* wvT   = ws + off; off += 24576;
    float* w1Tk  = ws + off; off += 24576;
    float* w1Tv  = ws + off; off += 24576;
    float* w2Tk  = ws + off; off += 6144;
    float* w2Tv  = ws + off; off += 6144;
    float* wvlT  = ws + off; off += 6144;
    float* cenT  = ws + off; off += 98304;
    float* outT  = ws + off; off += 98304;
    float* partial = ws + off; off += 2048;

    k_init<<<2720, 256, 0, stream>>>(wq, wk, wv, wkn1_w, wvn1_w, wkn2_w, wvn2_w,
                                     wvl_w, cen_w, out_w,
                                     wqT, wkT, wvT, w1Tk, w1Tv, w2Tk, w2Tv, wvlT, cenT, outT,
                                     state, ppv, w_prot, b_prot, w_lig, b_lig, h_a, pos);
    k_knn<<<cN + TABN / 4 + cB * cN / 2, 256, 0, stream>>>(
        pos, nbrb, distb,
        w1Tk, wkn1_b, w2Tk, wkn2_b, w1Tv, wvn1_b, w2Tv, wvn2_b, tabb,
        h_a, wqT, wkT, wvT, qA, kA, vA);

    float* hc = h_a;
    float* hn = h_b;
    for (int l = 0; l < cL; l++) {
        float* qr = (l & 1) ? qB : qA;
        __half* kr = (l & 1) ? kB : kA;
        __half* vr = (l & 1) ? vB : vA;
        float* qw2 = (l & 1) ? qA : qB;
        __half* kw2 = (l & 1) ? kA : kB;
        __half* vw2 = (l & 1) ? vA : vB;
        k_attn<<<cB * cN / 2, 256, 0, stream>>>(l, hc, qr, kr, vr, nbrb, distb, tabb,
            wkl_w, wvlT, wvl_b, cenT, cen_b, outT, out_b, ln_g, ln_b,
            hn, qw2, kw2, vw2, wqT, wkT, wvT);
        float* tmp = hc; hc = hn; hn = tmp;
    }

    k_fc1p<<<512, 256, 0, stream>>>(hc, fc1_w, partial);
    k_head2<<<1, 512, 0, stream>>>(partial, fc1_b, fc2_w, fc2_b, fc3_w, fc3_b, (float*)d_out);
}